// Round 9
// baseline (1451.487 us; speedup 1.0000x reference)
//
#include <hip/hip_runtime.h>
#include <math.h>

#define N_NODES 100000
#define N_EDGES 1600000
#define NBUK 782          // dst>>7 -> 0..781 (128 nodes per bucket)
#define BCAP 2600         // entries per bucket region (mean 2046, +12 sigma)
#define BINCHUNK 4096     // edges per k_bin block (256 thr x 16)

typedef unsigned short u16;
typedef u16 u16x4 __attribute__((ext_vector_type(4)));
typedef u16 u16x8 __attribute__((ext_vector_type(8)));
typedef short s16x8 __attribute__((ext_vector_type(8)));
typedef float f32x4 __attribute__((ext_vector_type(4)));

__device__ __forceinline__ float bf2f(u16 u) {
    union { unsigned i; float f; } v; v.i = ((unsigned)u) << 16; return v.f;
}
__device__ __forceinline__ u16 f2bf(float f) {
    union { float f; unsigned i; } v; v.f = f;
    return (u16)((v.i + 0x7FFFu + ((v.i >> 16) & 1u)) >> 16);  // RNE
}

// ---------------------------------------------------------------- binning ---
// Pack (dst&127)<<17 | src into per-bucket regions (bucket = dst>>7).
__global__ __launch_bounds__(256) void k_bin(const int* __restrict__ src,
                                             const int* __restrict__ dst,
                                             int* bucketCursor,
                                             unsigned int* __restrict__ bins) {
    __shared__ int lcnt[NBUK];
    __shared__ int lbase[NBUK];
    const int t = threadIdx.x;
    for (int i = t; i < NBUK; i += 256) lcnt[i] = 0;
    __syncthreads();

    const int e0 = blockIdx.x * BINCHUNK + t * 16;
    int4 s4[4], d4[4];
    int bkt[16], rnk[16];
    const bool valid = e0 < N_EDGES;   // N_EDGES % 16 == 0
    if (valid) {
        #pragma unroll
        for (int k = 0; k < 4; ++k) {
            s4[k] = *(const int4*)(src + e0 + 4 * k);
            d4[k] = *(const int4*)(dst + e0 + 4 * k);
        }
        #pragma unroll
        for (int k = 0; k < 4; ++k) {
            int dd[4] = { d4[k].x, d4[k].y, d4[k].z, d4[k].w };
            #pragma unroll
            for (int j = 0; j < 4; ++j) {
                int b = dd[j] >> 7;
                bkt[4 * k + j] = b;
                rnk[4 * k + j] = atomicAdd(&lcnt[b], 1);
            }
        }
    }
    __syncthreads();
    for (int i = t; i < NBUK; i += 256)
        if (lcnt[i] > 0) lbase[i] = atomicAdd(&bucketCursor[i], lcnt[i]);
    __syncthreads();
    if (valid) {
        #pragma unroll
        for (int k = 0; k < 4; ++k) {
            int ss[4] = { s4[k].x, s4[k].y, s4[k].z, s4[k].w };
            int dd[4] = { d4[k].x, d4[k].y, d4[k].z, d4[k].w };
            #pragma unroll
            for (int j = 0; j < 4; ++j) {
                int i = 4 * k + j;
                unsigned w = ((unsigned)(dd[j] & 127) << 17) | (unsigned)ss[j];
                bins[(size_t)bkt[i] * BCAP + lbase[bkt[i]] + rnk[i]] = w;
            }
        }
    }
}

// ----------------------------------- per-bucket degree -> dinv; pad tails ---
__global__ __launch_bounds__(256) void k_dinv(unsigned int* __restrict__ bins,
                                              const int* __restrict__ bucketCursor,
                                              float* __restrict__ dinv) {
    __shared__ int cnt[128];
    const int t = threadIdx.x;
    const int bkt = blockIdx.x;
    if (t < 128) cnt[t] = 0;
    __syncthreads();
    const int bcnt = bucketCursor[bkt];
    unsigned int* mybins = bins + (size_t)bkt * BCAP;
    for (int i = t; i < bcnt; i += 256) atomicAdd(&cnt[mybins[i] >> 17], 1);
    // pad to multiple of 8 with harmless entries (dl=0, src=zero row)
    const int pad = (bcnt + 7) & ~7;
    if (t < pad - bcnt) mybins[bcnt + t] = (unsigned)N_NODES;
    __syncthreads();
    if (t < 128) {
        int node = (bkt << 7) + t;
        if (node < N_NODES) dinv[node] = rsqrtf((float)(cnt[t] + 1));
    }
}

// ------------------------------------------------------- GEMM1 (MFMA) -------
// C = (x @ W1) * dinv via hi/lo bf16 split. Rows >= N_NODES get zeros (the
// zero row used by padding entries lives at row N_NODES).
__global__ __launch_bounds__(256) void k_gemm1(const float* __restrict__ X,
                                               const float* __restrict__ W,
                                               const float* __restrict__ dinv,
                                               u16* __restrict__ H) {
    __shared__ u16 sxh[64 * 128];
    __shared__ u16 sxl[64 * 128];
    __shared__ u16 wth[64 * 128];
    __shared__ u16 wtl[64 * 128];
    const int t = threadIdx.x;
    const int blk = blockIdx.x;

    {
        const float4* Xv = (const float4*)X;
        #pragma unroll
        for (int i = 0; i < 8; ++i) {
            int idx = i * 256 + t;
            int row = idx >> 5;
            int k4  = (idx & 31) << 2;
            int grow = blk * 64 + row;
            float4 v = make_float4(0.f, 0.f, 0.f, 0.f);
            if (grow < N_NODES) v = Xv[(size_t)grow * 32 + (idx & 31)];
            float f[4] = { v.x, v.y, v.z, v.w };
            u16x4 hv, lv;
            #pragma unroll
            for (int j = 0; j < 4; ++j) {
                u16 h = f2bf(f[j]);
                hv[j] = h;
                lv[j] = f2bf(f[j] - bf2f(h));
            }
            int byte = (row * 256 + k4 * 2) ^ ((row & 7) << 4);
            *(u16x4*)((char*)sxh + byte) = hv;
            *(u16x4*)((char*)sxl + byte) = lv;
        }
    }
    {
        const float4* Wv = (const float4*)W;
        #pragma unroll
        for (int i = 0; i < 8; ++i) {
            int idx = i * 256 + t;
            int k  = idx >> 4;
            int c0 = (idx & 15) << 2;
            float4 v = Wv[idx];
            float f[4] = { v.x, v.y, v.z, v.w };
            #pragma unroll
            for (int j = 0; j < 4; ++j) {
                int c = c0 + j;
                int byte = (c * 256 + k * 2) ^ ((c & 7) << 4);
                u16 h = f2bf(f[j]);
                *(u16*)((char*)wth + byte) = h;
                *(u16*)((char*)wtl + byte) = f2bf(f[j] - bf2f(h));
            }
        }
    }
    __syncthreads();

    const int lane = t & 63;
    const int w    = t >> 6;
    const int l16  = lane & 15;
    const int kg   = lane >> 4;
    f32x4 acc[4];
    #pragma unroll
    for (int nt = 0; nt < 4; ++nt)
        #pragma unroll
        for (int j = 0; j < 4; ++j) acc[nt][j] = 0.f;

    const int arow = w * 16 + l16;
    const int aswz = (arow & 7) << 4;
    #pragma unroll
    for (int kt = 0; kt < 4; ++kt) {
        const int koff = kt * 64 + kg * 16;
        s16x8 ah = *(const s16x8*)((const char*)sxh + ((arow * 256 + koff) ^ aswz));
        s16x8 al = *(const s16x8*)((const char*)sxl + ((arow * 256 + koff) ^ aswz));
        #pragma unroll
        for (int nt = 0; nt < 4; ++nt) {
            const int c = nt * 16 + l16;
            const int wb = (c * 256 + koff) ^ ((c & 7) << 4);
            s16x8 bh = *(const s16x8*)((const char*)wth + wb);
            s16x8 bl = *(const s16x8*)((const char*)wtl + wb);
            acc[nt] = __builtin_amdgcn_mfma_f32_16x16x32_bf16(ah, bh, acc[nt], 0, 0, 0);
            acc[nt] = __builtin_amdgcn_mfma_f32_16x16x32_bf16(ah, bl, acc[nt], 0, 0, 0);
            acc[nt] = __builtin_amdgcn_mfma_f32_16x16x32_bf16(al, bh, acc[nt], 0, 0, 0);
        }
    }
    const int rbase = blk * 64 + w * 16 + kg * 4;
    #pragma unroll
    for (int reg = 0; reg < 4; ++reg) {
        int row = rbase + reg;
        float di = (row < N_NODES) ? dinv[row] : 0.f;
        #pragma unroll
        for (int nt = 0; nt < 4; ++nt)
            H[(size_t)row * 64 + nt * 16 + l16] = f2bf(acc[nt][reg] * di);
    }
}

// ------------------------------------------------------- GEMM2 (MFMA) -------
__global__ __launch_bounds__(256) void k_gemm2(const u16* __restrict__ Xb,
                                               const float* __restrict__ W,
                                               const float* __restrict__ dinv,
                                               u16* __restrict__ H) {
    __shared__ u16 sxb[64 * 64];
    __shared__ u16 wth[64 * 64];
    __shared__ u16 wtl[64 * 64];
    const int t = threadIdx.x;
    const int blk = blockIdx.x;

    {
        const u16x8* Xv = (const u16x8*)Xb;
        #pragma unroll
        for (int i = 0; i < 2; ++i) {
            int idx = i * 256 + t;
            int row = idx >> 3;
            int k0  = (idx & 7) << 3;
            int grow = blk * 64 + row;
            u16x8 v;
            #pragma unroll
            for (int j = 0; j < 8; ++j) v[j] = 0;
            if (grow < N_NODES) v = Xv[(size_t)grow * 8 + (idx & 7)];
            int byte = (row * 128 + k0 * 2) ^ ((row & 7) << 4);
            *(u16x8*)((char*)sxb + byte) = v;
        }
    }
    {
        const float4* Wv = (const float4*)W;
        #pragma unroll
        for (int i = 0; i < 4; ++i) {
            int idx = i * 256 + t;
            int k  = idx >> 4;
            int c0 = (idx & 15) << 2;
            float4 v = Wv[idx];
            float f[4] = { v.x, v.y, v.z, v.w };
            #pragma unroll
            for (int j = 0; j < 4; ++j) {
                int c = c0 + j;
                int byte = (c * 128 + k * 2) ^ ((c & 7) << 4);
                u16 h = f2bf(f[j]);
                *(u16*)((char*)wth + byte) = h;
                *(u16*)((char*)wtl + byte) = f2bf(f[j] - bf2f(h));
            }
        }
    }
    __syncthreads();

    const int lane = t & 63;
    const int w    = t >> 6;
    const int l16  = lane & 15;
    const int kg   = lane >> 4;
    f32x4 acc[4];
    #pragma unroll
    for (int nt = 0; nt < 4; ++nt)
        #pragma unroll
        for (int j = 0; j < 4; ++j) acc[nt][j] = 0.f;

    const int arow = w * 16 + l16;
    const int aswz = (arow & 7) << 4;
    #pragma unroll
    for (int kt = 0; kt < 2; ++kt) {
        const int koff = kt * 64 + kg * 16;
        s16x8 a = *(const s16x8*)((const char*)sxb + ((arow * 128 + koff) ^ aswz));
        #pragma unroll
        for (int nt = 0; nt < 4; ++nt) {
            const int c = nt * 16 + l16;
            const int wb = (c * 128 + koff) ^ ((c & 7) << 4);
            s16x8 bh = *(const s16x8*)((const char*)wth + wb);
            s16x8 bl = *(const s16x8*)((const char*)wtl + wb);
            acc[nt] = __builtin_amdgcn_mfma_f32_16x16x32_bf16(a, bh, acc[nt], 0, 0, 0);
            acc[nt] = __builtin_amdgcn_mfma_f32_16x16x32_bf16(a, bl, acc[nt], 0, 0, 0);
        }
    }
    const int rbase = blk * 64 + w * 16 + kg * 4;
    #pragma unroll
    for (int reg = 0; reg < 4; ++reg) {
        int row = rbase + reg;
        float di = (row < N_NODES) ? dinv[row] : 0.f;
        #pragma unroll
        for (int nt = 0; nt < 4; ++nt)
            H[(size_t)row * 64 + nt * 16 + l16] = f2bf(acc[nt][reg] * di);
    }
}

// -------------------------------------------- aggregate via LDS scatter -----
// Block = bucket (128 dst nodes). acc[128][64] fp32 in LDS (32 KB). Per entry:
// gather hs[src] (2 B/lane, 128 B/wave) and LDS-atomicAdd into row dst&127
// (conflict-free: lane i -> bank i%32). No CSR, no per-node loops.
template <bool GELU>
__global__ __launch_bounds__(256) void k_agg(const u16* __restrict__ hs,
                                             const unsigned int* __restrict__ bins,
                                             const int* __restrict__ bucketCursor,
                                             const float* __restrict__ dinv,
                                             const float* __restrict__ b,
                                             void* __restrict__ outraw) {
    __shared__ float acc[128 * 64];
    const int t = threadIdx.x;
    const int bkt = blockIdx.x;
    {
        float4* accv = (float4*)acc;
        #pragma unroll
        for (int i = 0; i < 8; ++i)
            accv[i * 256 + t] = make_float4(0.f, 0.f, 0.f, 0.f);
    }
    __syncthreads();

    const int bcnt = bucketCursor[bkt];
    const unsigned int* mybins = bins + (size_t)bkt * BCAP;
    const int lane = t & 63;
    const int w = t >> 6;
    const unsigned laneB = (unsigned)(lane << 1);
    const char* hsB = (const char*)hs;
    const int bcnt8 = (bcnt + 7) & ~7;   // tail padded by k_dinv

    for (int i = w * 8; i < bcnt8; i += 32) {
        uint4 qa = *(const uint4*)(mybins + i);
        uint4 qb = *(const uint4*)(mybins + i + 4);
        unsigned e0 = qa.x, e1 = qa.y, e2 = qa.z, e3 = qa.w;
        unsigned e4 = qb.x, e5 = qb.y, e6 = qb.z, e7 = qb.w;
        float v0 = bf2f(*(const u16*)(hsB + (((e0 & 0x1FFFFu) << 7) + laneB)));
        float v1 = bf2f(*(const u16*)(hsB + (((e1 & 0x1FFFFu) << 7) + laneB)));
        float v2 = bf2f(*(const u16*)(hsB + (((e2 & 0x1FFFFu) << 7) + laneB)));
        float v3 = bf2f(*(const u16*)(hsB + (((e3 & 0x1FFFFu) << 7) + laneB)));
        float v4 = bf2f(*(const u16*)(hsB + (((e4 & 0x1FFFFu) << 7) + laneB)));
        float v5 = bf2f(*(const u16*)(hsB + (((e5 & 0x1FFFFu) << 7) + laneB)));
        float v6 = bf2f(*(const u16*)(hsB + (((e6 & 0x1FFFFu) << 7) + laneB)));
        float v7 = bf2f(*(const u16*)(hsB + (((e7 & 0x1FFFFu) << 7) + laneB)));
        atomicAdd(&acc[((e0 >> 17) << 6) + lane], v0);
        atomicAdd(&acc[((e1 >> 17) << 6) + lane], v1);
        atomicAdd(&acc[((e2 >> 17) << 6) + lane], v2);
        atomicAdd(&acc[((e3 >> 17) << 6) + lane], v3);
        atomicAdd(&acc[((e4 >> 17) << 6) + lane], v4);
        atomicAdd(&acc[((e5 >> 17) << 6) + lane], v5);
        atomicAdd(&acc[((e6 >> 17) << 6) + lane], v6);
        atomicAdd(&acc[((e7 >> 17) << 6) + lane], v7);
    }
    __syncthreads();

    // epilogue: 128 rows x 64 cols; c == lane for every iteration
    const int n0 = bkt << 7;
    const float bb = b[lane];
    #pragma unroll 4
    for (int i = 0; i < 32; ++i) {
        int idx = i * 256 + t;
        int node = n0 + (idx >> 6);
        if (node < N_NODES) {
            float val = acc[idx] + bf2f(hs[((size_t)node << 6) + lane]);  // + self
            float r = dinv[node] * val + bb;
            if (GELU) {
                r = 0.5f * r * (1.0f + erff(r * 0.70710678118654752f));
                ((u16*)outraw)[((size_t)node << 6) + lane] = f2bf(r);
            } else {
                ((float*)outraw)[((size_t)node << 6) + lane] = r;
            }
        }
    }
}

// ---------------------------------------------------------------- launch ----
extern "C" void kernel_launch(void* const* d_in, const int* in_sizes, int n_in,
                              void* d_out, int out_size, void* d_ws, size_t ws_size,
                              hipStream_t stream) {
    const float* x  = (const float*)d_in[0];
    const int* edge = (const int*)d_in[1];           // [2, N_EDGES] int32
    const float* W1 = (const float*)d_in[2];
    const float* b1 = (const float*)d_in[3];
    const float* W2 = (const float*)d_in[4];
    const float* b2 = (const float*)d_in[5];
    float* out = (float*)d_out;                      // [N_NODES, 64] fp32

    const int* src = edge;
    const int* dst = edge + N_EDGES;

    char* ws = (char*)d_ws;
    int*          bucketCursor = (int*)(ws);              // 782 ints (4 KB pad)
    float*        dinv = (float*)(ws + 4096);             // N (ends 404096)
    unsigned int* bins = (unsigned int*)(ws + 404096);    // 782*2600*4 = 8.13 MB (ends 8536896)
    u16*          hsb  = (u16*)(ws + 8536896);            // 100032*64 bf16 (ends 21340992)
    u16*          out1b= (u16*)(ws + 21340992);           // 100032*64 bf16 (ends 34145088)

    const int nBlkBin  = (N_EDGES + BINCHUNK - 1) / BINCHUNK;  // 391
    const int nBlkGemm = (N_NODES + 63) / 64;                  // 1563 (covers 100032)

    // ---- binning + dinv ----
    hipMemsetAsync(bucketCursor, 0, NBUK * sizeof(int), stream);
    k_bin<<<nBlkBin, 256, 0, stream>>>(src, dst, bucketCursor, bins);
    k_dinv<<<NBUK, 256, 0, stream>>>(bins, bucketCursor, dinv);

    // ---- layer 1 ----
    k_gemm1<<<nBlkGemm, 256, 0, stream>>>(x, W1, dinv, hsb);
    k_agg<true><<<NBUK, 256, 0, stream>>>(hsb, bins, bucketCursor, dinv, b1, out1b);

    // ---- layer 2 ----
    k_gemm2<<<nBlkGemm, 256, 0, stream>>>(out1b, W2, dinv, hsb);
    k_agg<false><<<NBUK, 256, 0, stream>>>(hsb, bins, bucketCursor, dinv, b2, out);
}

// Round 10
// 181.345 us; speedup vs baseline: 8.0040x; 8.0040x over previous
//
#include <hip/hip_runtime.h>
#include <math.h>

#define N_NODES 100000
#define N_EDGES 1600000
#define NBUK 782          // dst>>7 -> 0..781 (128 nodes per bucket)
#define BCAP 2600         // entries per bucket region (mean 2046)
#define BINCHUNK 4096     // edges per k_bin block (256 thr x 16)

typedef unsigned short u16;
typedef u16 u16x4 __attribute__((ext_vector_type(4)));
typedef u16 u16x8 __attribute__((ext_vector_type(8)));
typedef short s16x8 __attribute__((ext_vector_type(8)));
typedef float f32x4 __attribute__((ext_vector_type(4)));

__device__ __forceinline__ float bf2f(u16 u) {
    union { unsigned i; float f; } v; v.i = ((unsigned)u) << 16; return v.f;
}
__device__ __forceinline__ u16 f2bf(float f) {
    union { float f; unsigned i; } v; v.f = f;
    return (u16)((v.i + 0x7FFFu + ((v.i >> 16) & 1u)) >> 16);  // RNE
}

// ---------------------------------------------------------------- binning ---
// Pack (dst&127)<<17 | src into per-bucket regions (bucket = dst>>7).
__global__ __launch_bounds__(256) void k_bin(const int* __restrict__ src,
                                             const int* __restrict__ dst,
                                             int* bucketCursor,
                                             unsigned int* __restrict__ bins) {
    __shared__ int lcnt[NBUK];
    __shared__ int lbase[NBUK];
    const int t = threadIdx.x;
    for (int i = t; i < NBUK; i += 256) lcnt[i] = 0;
    __syncthreads();

    const int e0 = blockIdx.x * BINCHUNK + t * 16;
    int4 s4[4], d4[4];
    int bkt[16], rnk[16];
    const bool valid = e0 < N_EDGES;   // N_EDGES % 16 == 0
    if (valid) {
        #pragma unroll
        for (int k = 0; k < 4; ++k) {
            s4[k] = *(const int4*)(src + e0 + 4 * k);
            d4[k] = *(const int4*)(dst + e0 + 4 * k);
        }
        #pragma unroll
        for (int k = 0; k < 4; ++k) {
            int dd[4] = { d4[k].x, d4[k].y, d4[k].z, d4[k].w };
            #pragma unroll
            for (int j = 0; j < 4; ++j) {
                int b = dd[j] >> 7;
                bkt[4 * k + j] = b;
                rnk[4 * k + j] = atomicAdd(&lcnt[b], 1);
            }
        }
    }
    __syncthreads();
    for (int i = t; i < NBUK; i += 256)
        if (lcnt[i] > 0) lbase[i] = atomicAdd(&bucketCursor[i], lcnt[i]);
    __syncthreads();
    if (valid) {
        #pragma unroll
        for (int k = 0; k < 4; ++k) {
            int ss[4] = { s4[k].x, s4[k].y, s4[k].z, s4[k].w };
            int dd[4] = { d4[k].x, d4[k].y, d4[k].z, d4[k].w };
            #pragma unroll
            for (int j = 0; j < 4; ++j) {
                int i = 4 * k + j;
                unsigned w = ((unsigned)(dd[j] & 127) << 17) | (unsigned)ss[j];
                bins[(size_t)bkt[i] * BCAP + lbase[bkt[i]] + rnk[i]] = w;
            }
        }
    }
}

// ------------------------------------------------- bucket-total scan (1 wg) -
__global__ __launch_bounds__(256) void k_bscan(const int* __restrict__ bucketCursor,
                                               int* __restrict__ gBase,
                                               int* __restrict__ row_start) {
    __shared__ int sd[256];
    const int t = threadIdx.x;
    const int idx0 = t * 4;
    int v0 = (idx0 + 0 < NBUK) ? bucketCursor[idx0 + 0] : 0;
    int v1 = (idx0 + 1 < NBUK) ? bucketCursor[idx0 + 1] : 0;
    int v2 = (idx0 + 2 < NBUK) ? bucketCursor[idx0 + 2] : 0;
    int v3 = (idx0 + 3 < NBUK) ? bucketCursor[idx0 + 3] : 0;
    int s0 = v0, s1 = s0 + v1, s2 = s1 + v2, s3 = s2 + v3;
    sd[t] = s3;
    __syncthreads();
    #pragma unroll
    for (int off = 1; off < 256; off <<= 1) {
        int x = (t >= off) ? sd[t - off] : 0;
        __syncthreads();
        sd[t] += x;
        __syncthreads();
    }
    int excl = (t > 0) ? sd[t - 1] : 0;
    if (idx0 + 0 < NBUK) gBase[idx0 + 0] = excl;
    if (idx0 + 1 < NBUK) gBase[idx0 + 1] = excl + s0;
    if (idx0 + 2 < NBUK) gBase[idx0 + 2] = excl + s1;
    if (idx0 + 3 < NBUK) gBase[idx0 + 3] = excl + s2;
    if (t == 0) row_start[N_NODES] = N_EDGES;
}

// ------------------------------------------- per-bucket CSR build (128) -----
__global__ __launch_bounds__(256) void k_build(const unsigned int* __restrict__ bins,
                                               const int* __restrict__ bucketCursor,
                                               const int* __restrict__ gBase,
                                               int* __restrict__ row_start,
                                               float* __restrict__ dinv,
                                               int* __restrict__ csr_src) {
    __shared__ int cnt[128];
    __shared__ int ps[128];
    __shared__ int cur[128];
    const int b = blockIdx.x;
    const int t = threadIdx.x;
    const int bcnt = bucketCursor[b];
    const int gb = gBase[b];
    const unsigned int* mybins = bins + (size_t)b * BCAP;

    if (t < 128) cnt[t] = 0;
    __syncthreads();
    for (int i = t; i < bcnt; i += 256)
        atomicAdd(&cnt[mybins[i] >> 17], 1);
    __syncthreads();
    if (t < 128) ps[t] = cnt[t];
    __syncthreads();
    #pragma unroll
    for (int off = 1; off < 128; off <<= 1) {
        int x = (t >= off && t < 128) ? ps[t - off] : 0;
        __syncthreads();
        if (t < 128) ps[t] += x;
        __syncthreads();
    }
    if (t < 128) {
        int excl = (t > 0) ? ps[t - 1] : 0;
        cur[t] = excl;
        int node = (b << 7) + t;
        if (node < N_NODES) {
            row_start[node] = gb + excl;
            dinv[node] = rsqrtf((float)(cnt[t] + 1));
        }
    }
    __syncthreads();
    for (int i = t; i < bcnt; i += 256) {
        unsigned w = mybins[i];
        int dl = w >> 17;
        int s = (int)(w & 0x1FFFFu);
        int p = atomicAdd(&cur[dl], 1);
        csr_src[gb + p] = s;
    }
}

// ------------------------------------------------------- GEMM1 (MFMA) -------
// C = (x @ W1) * dinv via hi/lo bf16 split. Rows >= N_NODES get zeros (the
// aggregate's dummy-gather zero row lives at row N_NODES). H stored with
// non-temporal hint so the gather table isn't left dirty in per-XCD L2.
__global__ __launch_bounds__(256) void k_gemm1(const float* __restrict__ X,
                                               const float* __restrict__ W,
                                               const float* __restrict__ dinv,
                                               u16* __restrict__ H) {
    __shared__ u16 sxh[64 * 128];
    __shared__ u16 sxl[64 * 128];
    __shared__ u16 wth[64 * 128];
    __shared__ u16 wtl[64 * 128];
    const int t = threadIdx.x;
    const int blk = blockIdx.x;

    {
        const float4* Xv = (const float4*)X;
        #pragma unroll
        for (int i = 0; i < 8; ++i) {
            int idx = i * 256 + t;
            int row = idx >> 5;
            int k4  = (idx & 31) << 2;
            int grow = blk * 64 + row;
            float4 v = make_float4(0.f, 0.f, 0.f, 0.f);
            if (grow < N_NODES) v = Xv[(size_t)grow * 32 + (idx & 31)];
            float f[4] = { v.x, v.y, v.z, v.w };
            u16x4 hv, lv;
            #pragma unroll
            for (int j = 0; j < 4; ++j) {
                u16 h = f2bf(f[j]);
                hv[j] = h;
                lv[j] = f2bf(f[j] - bf2f(h));
            }
            int byte = (row * 256 + k4 * 2) ^ ((row & 7) << 4);
            *(u16x4*)((char*)sxh + byte) = hv;
            *(u16x4*)((char*)sxl + byte) = lv;
        }
    }
    {
        const float4* Wv = (const float4*)W;
        #pragma unroll
        for (int i = 0; i < 8; ++i) {
            int idx = i * 256 + t;
            int k  = idx >> 4;
            int c0 = (idx & 15) << 2;
            float4 v = Wv[idx];
            float f[4] = { v.x, v.y, v.z, v.w };
            #pragma unroll
            for (int j = 0; j < 4; ++j) {
                int c = c0 + j;
                int byte = (c * 256 + k * 2) ^ ((c & 7) << 4);
                u16 h = f2bf(f[j]);
                *(u16*)((char*)wth + byte) = h;
                *(u16*)((char*)wtl + byte) = f2bf(f[j] - bf2f(h));
            }
        }
    }
    __syncthreads();

    const int lane = t & 63;
    const int w    = t >> 6;
    const int l16  = lane & 15;
    const int kg   = lane >> 4;
    f32x4 acc[4];
    #pragma unroll
    for (int nt = 0; nt < 4; ++nt)
        #pragma unroll
        for (int j = 0; j < 4; ++j) acc[nt][j] = 0.f;

    const int arow = w * 16 + l16;
    const int aswz = (arow & 7) << 4;
    #pragma unroll
    for (int kt = 0; kt < 4; ++kt) {
        const int koff = kt * 64 + kg * 16;
        s16x8 ah = *(const s16x8*)((const char*)sxh + ((arow * 256 + koff) ^ aswz));
        s16x8 al = *(const s16x8*)((const char*)sxl + ((arow * 256 + koff) ^ aswz));
        #pragma unroll
        for (int nt = 0; nt < 4; ++nt) {
            const int c = nt * 16 + l16;
            const int wb = (c * 256 + koff) ^ ((c & 7) << 4);
            s16x8 bh = *(const s16x8*)((const char*)wth + wb);
            s16x8 bl = *(const s16x8*)((const char*)wtl + wb);
            acc[nt] = __builtin_amdgcn_mfma_f32_16x16x32_bf16(ah, bh, acc[nt], 0, 0, 0);
            acc[nt] = __builtin_amdgcn_mfma_f32_16x16x32_bf16(ah, bl, acc[nt], 0, 0, 0);
            acc[nt] = __builtin_amdgcn_mfma_f32_16x16x32_bf16(al, bh, acc[nt], 0, 0, 0);
        }
    }
    const int rbase = blk * 64 + w * 16 + kg * 4;
    #pragma unroll
    for (int reg = 0; reg < 4; ++reg) {
        int row = rbase + reg;
        float di = (row < N_NODES) ? dinv[row] : 0.f;
        #pragma unroll
        for (int nt = 0; nt < 4; ++nt)
            __builtin_nontemporal_store(f2bf(acc[nt][reg] * di),
                                        &H[(size_t)row * 64 + nt * 16 + l16]);
    }
}

// ------------------------------------------------------- GEMM2 (MFMA) -------
__global__ __launch_bounds__(256) void k_gemm2(const u16* __restrict__ Xb,
                                               const float* __restrict__ W,
                                               const float* __restrict__ dinv,
                                               u16* __restrict__ H) {
    __shared__ u16 sxb[64 * 64];
    __shared__ u16 wth[64 * 64];
    __shared__ u16 wtl[64 * 64];
    const int t = threadIdx.x;
    const int blk = blockIdx.x;

    {
        const u16x8* Xv = (const u16x8*)Xb;
        #pragma unroll
        for (int i = 0; i < 2; ++i) {
            int idx = i * 256 + t;
            int row = idx >> 3;
            int k0  = (idx & 7) << 3;
            int grow = blk * 64 + row;
            u16x8 v;
            #pragma unroll
            for (int j = 0; j < 8; ++j) v[j] = 0;
            if (grow < N_NODES) v = Xv[(size_t)grow * 8 + (idx & 7)];
            int byte = (row * 128 + k0 * 2) ^ ((row & 7) << 4);
            *(u16x8*)((char*)sxb + byte) = v;
        }
    }
    {
        const float4* Wv = (const float4*)W;
        #pragma unroll
        for (int i = 0; i < 4; ++i) {
            int idx = i * 256 + t;
            int k  = idx >> 4;
            int c0 = (idx & 15) << 2;
            float4 v = Wv[idx];
            float f[4] = { v.x, v.y, v.z, v.w };
            #pragma unroll
            for (int j = 0; j < 4; ++j) {
                int c = c0 + j;
                int byte = (c * 128 + k * 2) ^ ((c & 7) << 4);
                u16 h = f2bf(f[j]);
                *(u16*)((char*)wth + byte) = h;
                *(u16*)((char*)wtl + byte) = f2bf(f[j] - bf2f(h));
            }
        }
    }
    __syncthreads();

    const int lane = t & 63;
    const int w    = t >> 6;
    const int l16  = lane & 15;
    const int kg   = lane >> 4;
    f32x4 acc[4];
    #pragma unroll
    for (int nt = 0; nt < 4; ++nt)
        #pragma unroll
        for (int j = 0; j < 4; ++j) acc[nt][j] = 0.f;

    const int arow = w * 16 + l16;
    const int aswz = (arow & 7) << 4;
    #pragma unroll
    for (int kt = 0; kt < 2; ++kt) {
        const int koff = kt * 64 + kg * 16;
        s16x8 a = *(const s16x8*)((const char*)sxb + ((arow * 128 + koff) ^ aswz));
        #pragma unroll
        for (int nt = 0; nt < 4; ++nt) {
            const int c = nt * 16 + l16;
            const int wb = (c * 128 + koff) ^ ((c & 7) << 4);
            s16x8 bh = *(const s16x8*)((const char*)wth + wb);
            s16x8 bl = *(const s16x8*)((const char*)wtl + wb);
            acc[nt] = __builtin_amdgcn_mfma_f32_16x16x32_bf16(a, bh, acc[nt], 0, 0, 0);
            acc[nt] = __builtin_amdgcn_mfma_f32_16x16x32_bf16(a, bl, acc[nt], 0, 0, 0);
        }
    }
    const int rbase = blk * 64 + w * 16 + kg * 4;
    #pragma unroll
    for (int reg = 0; reg < 4; ++reg) {
        int row = rbase + reg;
        float di = (row < N_NODES) ? dinv[row] : 0.f;
        #pragma unroll
        for (int nt = 0; nt < 4; ++nt)
            __builtin_nontemporal_store(f2bf(acc[nt][reg] * di),
                                        &H[(size_t)row * 64 + nt * 16 + l16]);
    }
}

// ---------------------------------------------------------------- aggregate -
// 4 nodes/block (1/wave), lane = feature column. CSR indices staged into LDS
// slots of 32 per node (padded with the zero row N_NODES); deg>32 nodes use a
// global fallback. (Round-7 version — best measured.)
template <bool GELU>
__global__ __launch_bounds__(256) void k_aggregate(const u16* __restrict__ hs,
                                                   const int* __restrict__ csr_src,
                                                   const int* __restrict__ row_start,
                                                   const float* __restrict__ dinv,
                                                   const float* __restrict__ b,
                                                   void* __restrict__ outraw) {
    __shared__ int sIdx[128];
    __shared__ int sRS[5];
    const int t = threadIdx.x;
    const int n0 = blockIdx.x << 2;
    if (t < 5) sRS[t] = row_start[n0 + t];
    __syncthreads();
    if (t < 128) {
        int k = t >> 5, o = t & 31;
        int jsk = sRS[k];
        int degk = sRS[k + 1] - jsk;
        sIdx[t] = (o < degk) ? csr_src[jsk + o] : N_NODES;   // pad -> zero row
    }
    __syncthreads();

    const int w    = t >> 6;
    const int lane = t & 63;
    const int node = n0 + w;
    const int deg  = sRS[w + 1] - sRS[w];
    const size_t laneB = (size_t)(lane << 1);
    const char* hsB = (const char*)hs;

    float acc = bf2f(hs[((size_t)node << 6) + lane]);   // self-loop

    if (deg <= 32) {
        const int4* s4 = (const int4*)(sIdx + (w << 5));
#define GATH8(B) { \
        int4 qa = s4[2*(B)], qb = s4[2*(B)+1]; \
        u16 v0 = *(const u16*)(hsB + (((size_t)qa.x << 7) + laneB)); \
        u16 v1 = *(const u16*)(hsB + (((size_t)qa.y << 7) + laneB)); \
        u16 v2 = *(const u16*)(hsB + (((size_t)qa.z << 7) + laneB)); \
        u16 v3 = *(const u16*)(hsB + (((size_t)qa.w << 7) + laneB)); \
        u16 v4 = *(const u16*)(hsB + (((size_t)qb.x << 7) + laneB)); \
        u16 v5 = *(const u16*)(hsB + (((size_t)qb.y << 7) + laneB)); \
        u16 v6 = *(const u16*)(hsB + (((size_t)qb.z << 7) + laneB)); \
        u16 v7 = *(const u16*)(hsB + (((size_t)qb.w << 7) + laneB)); \
        acc += bf2f(v0); acc += bf2f(v1); acc += bf2f(v2); acc += bf2f(v3); \
        acc += bf2f(v4); acc += bf2f(v5); acc += bf2f(v6); acc += bf2f(v7); }
        if (deg > 0)  GATH8(0)
        if (deg > 8)  GATH8(1)
        if (deg > 16) GATH8(2)
        if (deg > 24) GATH8(3)
#undef GATH8
    } else {
        const int jS = sRS[w];
        const int jE = sRS[w + 1];
        int j = jS;
        for (; j + 8 <= jE; j += 8) {
            int r0 = csr_src[j + 0], r1 = csr_src[j + 1];
            int r2 = csr_src[j + 2], r3 = csr_src[j + 3];
            int r4 = csr_src[j + 4], r5 = csr_src[j + 5];
            int r6 = csr_src[j + 6], r7 = csr_src[j + 7];
            u16 v0 = *(const u16*)(hsB + (((size_t)r0 << 7) + laneB));
            u16 v1 = *(const u16*)(hsB + (((size_t)r1 << 7) + laneB));
            u16 v2 = *(const u16*)(hsB + (((size_t)r2 << 7) + laneB));
            u16 v3 = *(const u16*)(hsB + (((size_t)r3 << 7) + laneB));
            u16 v4 = *(const u16*)(hsB + (((size_t)r4 << 7) + laneB));
            u16 v5 = *(const u16*)(hsB + (((size_t)r5 << 7) + laneB));
            u16 v6 = *(const u16*)(hsB + (((size_t)r6 << 7) + laneB));
            u16 v7 = *(const u16*)(hsB + (((size_t)r7 << 7) + laneB));
            acc += bf2f(v0); acc += bf2f(v1); acc += bf2f(v2); acc += bf2f(v3);
            acc += bf2f(v4); acc += bf2f(v5); acc += bf2f(v6); acc += bf2f(v7);
        }
        for (; j < jE; ++j)
            acc += bf2f(*(const u16*)(hsB + (((size_t)csr_src[j] << 7) + laneB)));
    }

    float r = dinv[node] * acc + b[lane];
    if (GELU) {
        r = 0.5f * r * (1.0f + erff(r * 0.70710678118654752f));
        ((u16*)outraw)[((size_t)node << 6) + lane] = f2bf(r);
    } else {
        ((float*)outraw)[((size_t)node << 6) + lane] = r;
    }
}

// ---------------------------------------------------------------- launch ----
extern "C" void kernel_launch(void* const* d_in, const int* in_sizes, int n_in,
                              void* d_out, int out_size, void* d_ws, size_t ws_size,
                              hipStream_t stream) {
    const float* x  = (const float*)d_in[0];
    const int* edge = (const int*)d_in[1];           // [2, N_EDGES] int32
    const float* W1 = (const float*)d_in[2];
    const float* b1 = (const float*)d_in[3];
    const float* W2 = (const float*)d_in[4];
    const float* b2 = (const float*)d_in[5];
    float* out = (float*)d_out;                      // [N_NODES, 64] fp32

    const int* src = edge;
    const int* dst = edge + N_EDGES;

    char* ws = (char*)d_ws;
    int*   bucketCursor = (int*)(ws);                 // 782 ints (pad 4096)
    int*   gBase        = (int*)(ws + 4096);          // 782 ints (pad 8192)
    int*   row_start    = (int*)(ws + 8192);          // N+1 (ends 408196 -> pad 408576)
    float* dinv         = (float*)(ws + 408576);      // N (ends 808576 -> pad 808960)
    int*   csr_src      = (int*)(ws + 808960);        // E (ends 7208960)
    u16*   hsb          = (u16*)(ws + 7208960);       // 100032*64 bf16 = 12.8MB (ends 20013056)
    unsigned int* bins  = (unsigned int*)hsb;         // 782*2600*4 = 8.13MB, dead before gemm1
    u16*   out1b        = (u16*)(ws + 20013056);      // 100032*64 bf16 (ends 32817152)

    const int nBlkBin  = (N_EDGES + BINCHUNK - 1) / BINCHUNK;  // 391
    const int nBlkGemm = (N_NODES + 63) / 64;                  // 1563 (covers 100032)
    const int nBlkAgg  = N_NODES / 4;                          // 25000

    // ---- CSR build ----
    hipMemsetAsync(bucketCursor, 0, NBUK * sizeof(int), stream);
    k_bin<<<nBlkBin, 256, 0, stream>>>(src, dst, bucketCursor, bins);
    k_bscan<<<1, 256, 0, stream>>>(bucketCursor, gBase, row_start);
    k_build<<<NBUK, 256, 0, stream>>>(bins, bucketCursor, gBase, row_start, dinv, csr_src);

    // ---- layer 1 ----
    k_gemm1<<<nBlkGemm, 256, 0, stream>>>(x, W1, dinv, hsb);
    k_aggregate<true><<<nBlkAgg, 256, 0, stream>>>(hsb, csr_src, row_start, dinv, b1, out1b);

    // ---- layer 2 ----
    k_gemm2<<<nBlkGemm, 256, 0, stream>>>(out1b, W2, dinv, hsb);
    k_aggregate<false><<<nBlkAgg, 256, 0, stream>>>(hsb, csr_src, row_start, dinv, b2, out);
}

// Round 11
// 167.522 us; speedup vs baseline: 8.6645x; 1.0825x over previous
//
#include <hip/hip_runtime.h>
#include <math.h>

#define N_NODES 100000
#define N_EDGES 1600000
#define NBUK 782          // dst>>7 -> 0..781 (128 nodes per bucket)
#define BCAP 2600         // entries per bucket region (mean 2046)
#define BINCHUNK 4096     // edges per k_bin block (256 thr x 16)

typedef unsigned short u16;
typedef u16 u16x4 __attribute__((ext_vector_type(4)));
typedef u16 u16x8 __attribute__((ext_vector_type(8)));
typedef short s16x8 __attribute__((ext_vector_type(8)));
typedef float f32x4 __attribute__((ext_vector_type(4)));

__device__ __forceinline__ float bf2f(u16 u) {
    union { unsigned i; float f; } v; v.i = ((unsigned)u) << 16; return v.f;
}
__device__ __forceinline__ u16 f2bf(float f) {
    union { float f; unsigned i; } v; v.f = f;
    return (u16)((v.i + 0x7FFFu + ((v.i >> 16) & 1u)) >> 16);  // RNE
}

// ---------------------------------------------------------------- binning ---
__global__ __launch_bounds__(256) void k_bin(const int* __restrict__ src,
                                             const int* __restrict__ dst,
                                             int* bucketCursor,
                                             unsigned int* __restrict__ bins) {
    __shared__ int lcnt[NBUK];
    __shared__ int lbase[NBUK];
    const int t = threadIdx.x;
    for (int i = t; i < NBUK; i += 256) lcnt[i] = 0;
    __syncthreads();

    const int e0 = blockIdx.x * BINCHUNK + t * 16;
    int4 s4[4], d4[4];
    int bkt[16], rnk[16];
    const bool valid = e0 < N_EDGES;   // N_EDGES % 16 == 0
    if (valid) {
        #pragma unroll
        for (int k = 0; k < 4; ++k) {
            s4[k] = *(const int4*)(src + e0 + 4 * k);
            d4[k] = *(const int4*)(dst + e0 + 4 * k);
        }
        #pragma unroll
        for (int k = 0; k < 4; ++k) {
            int dd[4] = { d4[k].x, d4[k].y, d4[k].z, d4[k].w };
            #pragma unroll
            for (int j = 0; j < 4; ++j) {
                int b = dd[j] >> 7;
                bkt[4 * k + j] = b;
                rnk[4 * k + j] = atomicAdd(&lcnt[b], 1);
            }
        }
    }
    __syncthreads();
    for (int i = t; i < NBUK; i += 256)
        if (lcnt[i] > 0) lbase[i] = atomicAdd(&bucketCursor[i], lcnt[i]);
    __syncthreads();
    if (valid) {
        #pragma unroll
        for (int k = 0; k < 4; ++k) {
            int ss[4] = { s4[k].x, s4[k].y, s4[k].z, s4[k].w };
            int dd[4] = { d4[k].x, d4[k].y, d4[k].z, d4[k].w };
            #pragma unroll
            for (int j = 0; j < 4; ++j) {
                int i = 4 * k + j;
                unsigned w = ((unsigned)(dd[j] & 127) << 17) | (unsigned)ss[j];
                bins[(size_t)bkt[i] * BCAP + lbase[bkt[i]] + rnk[i]] = w;
            }
        }
    }
}

// ------------------------------------------------- bucket-total scan (1 wg) -
__global__ __launch_bounds__(256) void k_bscan(const int* __restrict__ bucketCursor,
                                               int* __restrict__ gBase,
                                               int* __restrict__ row_start) {
    __shared__ int sd[256];
    const int t = threadIdx.x;
    const int idx0 = t * 4;
    int v0 = (idx0 + 0 < NBUK) ? bucketCursor[idx0 + 0] : 0;
    int v1 = (idx0 + 1 < NBUK) ? bucketCursor[idx0 + 1] : 0;
    int v2 = (idx0 + 2 < NBUK) ? bucketCursor[idx0 + 2] : 0;
    int v3 = (idx0 + 3 < NBUK) ? bucketCursor[idx0 + 3] : 0;
    int s0 = v0, s1 = s0 + v1, s2 = s1 + v2, s3 = s2 + v3;
    sd[t] = s3;
    __syncthreads();
    #pragma unroll
    for (int off = 1; off < 256; off <<= 1) {
        int x = (t >= off) ? sd[t - off] : 0;
        __syncthreads();
        sd[t] += x;
        __syncthreads();
    }
    int excl = (t > 0) ? sd[t - 1] : 0;
    if (idx0 + 0 < NBUK) gBase[idx0 + 0] = excl;
    if (idx0 + 1 < NBUK) gBase[idx0 + 1] = excl + s0;
    if (idx0 + 2 < NBUK) gBase[idx0 + 2] = excl + s1;
    if (idx0 + 3 < NBUK) gBase[idx0 + 3] = excl + s2;
    if (t == 0) row_start[N_NODES] = N_EDGES;
}

// ------------------------------------------- per-bucket CSR build (128) -----
__global__ __launch_bounds__(256) void k_build(const unsigned int* __restrict__ bins,
                                               const int* __restrict__ bucketCursor,
                                               const int* __restrict__ gBase,
                                               int* __restrict__ row_start,
                                               float* __restrict__ dinv,
                                               int* __restrict__ csr_src) {
    __shared__ int cnt[128];
    __shared__ int ps[128];
    __shared__ int cur[128];
    const int b = blockIdx.x;
    const int t = threadIdx.x;
    const int bcnt = bucketCursor[b];
    const int gb = gBase[b];
    const unsigned int* mybins = bins + (size_t)b * BCAP;

    if (t < 128) cnt[t] = 0;
    __syncthreads();
    for (int i = t; i < bcnt; i += 256)
        atomicAdd(&cnt[mybins[i] >> 17], 1);
    __syncthreads();
    if (t < 128) ps[t] = cnt[t];
    __syncthreads();
    #pragma unroll
    for (int off = 1; off < 128; off <<= 1) {
        int x = (t >= off && t < 128) ? ps[t - off] : 0;
        __syncthreads();
        if (t < 128) ps[t] += x;
        __syncthreads();
    }
    if (t < 128) {
        int excl = (t > 0) ? ps[t - 1] : 0;
        cur[t] = excl;
        int node = (b << 7) + t;
        if (node < N_NODES) {
            row_start[node] = gb + excl;
            dinv[node] = rsqrtf((float)(cnt[t] + 1));
        }
    }
    __syncthreads();
    for (int i = t; i < bcnt; i += 256) {
        unsigned w = mybins[i];
        int dl = w >> 17;
        int s = (int)(w & 0x1FFFFu);
        int p = atomicAdd(&cur[dl], 1);
        csr_src[gb + p] = s;
    }
}

// ------------------------------------------------------- GEMM1 (MFMA) -------
// C = (x @ W1) * dinv via hi/lo bf16 split. Rows >= N_NODES get zeros (the
// aggregate's dummy-gather zero row lives at row N_NODES).
__global__ __launch_bounds__(256) void k_gemm1(const float* __restrict__ X,
                                               const float* __restrict__ W,
                                               const float* __restrict__ dinv,
                                               u16* __restrict__ H) {
    __shared__ u16 sxh[64 * 128];
    __shared__ u16 sxl[64 * 128];
    __shared__ u16 wth[64 * 128];
    __shared__ u16 wtl[64 * 128];
    const int t = threadIdx.x;
    const int blk = blockIdx.x;

    {
        const float4* Xv = (const float4*)X;
        #pragma unroll
        for (int i = 0; i < 8; ++i) {
            int idx = i * 256 + t;
            int row = idx >> 5;
            int k4  = (idx & 31) << 2;
            int grow = blk * 64 + row;
            float4 v = make_float4(0.f, 0.f, 0.f, 0.f);
            if (grow < N_NODES) v = Xv[(size_t)grow * 32 + (idx & 31)];
            float f[4] = { v.x, v.y, v.z, v.w };
            u16x4 hv, lv;
            #pragma unroll
            for (int j = 0; j < 4; ++j) {
                u16 h = f2bf(f[j]);
                hv[j] = h;
                lv[j] = f2bf(f[j] - bf2f(h));
            }
            int byte = (row * 256 + k4 * 2) ^ ((row & 7) << 4);
            *(u16x4*)((char*)sxh + byte) = hv;
            *(u16x4*)((char*)sxl + byte) = lv;
        }
    }
    {
        const float4* Wv = (const float4*)W;
        #pragma unroll
        for (int i = 0; i < 8; ++i) {
            int idx = i * 256 + t;
            int k  = idx >> 4;
            int c0 = (idx & 15) << 2;
            float4 v = Wv[idx];
            float f[4] = { v.x, v.y, v.z, v.w };
            #pragma unroll
            for (int j = 0; j < 4; ++j) {
                int c = c0 + j;
                int byte = (c * 256 + k * 2) ^ ((c & 7) << 4);
                u16 h = f2bf(f[j]);
                *(u16*)((char*)wth + byte) = h;
                *(u16*)((char*)wtl + byte) = f2bf(f[j] - bf2f(h));
            }
        }
    }
    __syncthreads();

    const int lane = t & 63;
    const int w    = t >> 6;
    const int l16  = lane & 15;
    const int kg   = lane >> 4;
    f32x4 acc[4];
    #pragma unroll
    for (int nt = 0; nt < 4; ++nt)
        #pragma unroll
        for (int j = 0; j < 4; ++j) acc[nt][j] = 0.f;

    const int arow = w * 16 + l16;
    const int aswz = (arow & 7) << 4;
    #pragma unroll
    for (int kt = 0; kt < 4; ++kt) {
        const int koff = kt * 64 + kg * 16;
        s16x8 ah = *(const s16x8*)((const char*)sxh + ((arow * 256 + koff) ^ aswz));
        s16x8 al = *(const s16x8*)((const char*)sxl + ((arow * 256 + koff) ^ aswz));
        #pragma unroll
        for (int nt = 0; nt < 4; ++nt) {
            const int c = nt * 16 + l16;
            const int wb = (c * 256 + koff) ^ ((c & 7) << 4);
            s16x8 bh = *(const s16x8*)((const char*)wth + wb);
            s16x8 bl = *(const s16x8*)((const char*)wtl + wb);
            acc[nt] = __builtin_amdgcn_mfma_f32_16x16x32_bf16(ah, bh, acc[nt], 0, 0, 0);
            acc[nt] = __builtin_amdgcn_mfma_f32_16x16x32_bf16(ah, bl, acc[nt], 0, 0, 0);
            acc[nt] = __builtin_amdgcn_mfma_f32_16x16x32_bf16(al, bh, acc[nt], 0, 0, 0);
        }
    }
    const int rbase = blk * 64 + w * 16 + kg * 4;
    #pragma unroll
    for (int reg = 0; reg < 4; ++reg) {
        int row = rbase + reg;
        float di = (row < N_NODES) ? dinv[row] : 0.f;
        #pragma unroll
        for (int nt = 0; nt < 4; ++nt)
            __builtin_nontemporal_store(f2bf(acc[nt][reg] * di),
                                        &H[(size_t)row * 64 + nt * 16 + l16]);
    }
}

// ------------------------------------------------------- GEMM2 (MFMA) -------
__global__ __launch_bounds__(256) void k_gemm2(const u16* __restrict__ Xb,
                                               const float* __restrict__ W,
                                               const float* __restrict__ dinv,
                                               u16* __restrict__ H) {
    __shared__ u16 sxb[64 * 64];
    __shared__ u16 wth[64 * 64];
    __shared__ u16 wtl[64 * 64];
    const int t = threadIdx.x;
    const int blk = blockIdx.x;

    {
        const u16x8* Xv = (const u16x8*)Xb;
        #pragma unroll
        for (int i = 0; i < 2; ++i) {
            int idx = i * 256 + t;
            int row = idx >> 3;
            int k0  = (idx & 7) << 3;
            int grow = blk * 64 + row;
            u16x8 v;
            #pragma unroll
            for (int j = 0; j < 8; ++j) v[j] = 0;
            if (grow < N_NODES) v = Xv[(size_t)grow * 8 + (idx & 7)];
            int byte = (row * 128 + k0 * 2) ^ ((row & 7) << 4);
            *(u16x8*)((char*)sxb + byte) = v;
        }
    }
    {
        const float4* Wv = (const float4*)W;
        #pragma unroll
        for (int i = 0; i < 4; ++i) {
            int idx = i * 256 + t;
            int k  = idx >> 4;
            int c0 = (idx & 15) << 2;
            float4 v = Wv[idx];
            float f[4] = { v.x, v.y, v.z, v.w };
            #pragma unroll
            for (int j = 0; j < 4; ++j) {
                int c = c0 + j;
                int byte = (c * 128 + k * 2) ^ ((c & 7) << 4);
                u16 h = f2bf(f[j]);
                *(u16*)((char*)wth + byte) = h;
                *(u16*)((char*)wtl + byte) = f2bf(f[j] - bf2f(h));
            }
        }
    }
    __syncthreads();

    const int lane = t & 63;
    const int w    = t >> 6;
    const int l16  = lane & 15;
    const int kg   = lane >> 4;
    f32x4 acc[4];
    #pragma unroll
    for (int nt = 0; nt < 4; ++nt)
        #pragma unroll
        for (int j = 0; j < 4; ++j) acc[nt][j] = 0.f;

    const int arow = w * 16 + l16;
    const int aswz = (arow & 7) << 4;
    #pragma unroll
    for (int kt = 0; kt < 2; ++kt) {
        const int koff = kt * 64 + kg * 16;
        s16x8 a = *(const s16x8*)((const char*)sxb + ((arow * 128 + koff) ^ aswz));
        #pragma unroll
        for (int nt = 0; nt < 4; ++nt) {
            const int c = nt * 16 + l16;
            const int wb = (c * 128 + koff) ^ ((c & 7) << 4);
            s16x8 bh = *(const s16x8*)((const char*)wth + wb);
            s16x8 bl = *(const s16x8*)((const char*)wtl + wb);
            acc[nt] = __builtin_amdgcn_mfma_f32_16x16x32_bf16(a, bh, acc[nt], 0, 0, 0);
            acc[nt] = __builtin_amdgcn_mfma_f32_16x16x32_bf16(a, bl, acc[nt], 0, 0, 0);
        }
    }
    const int rbase = blk * 64 + w * 16 + kg * 4;
    #pragma unroll
    for (int reg = 0; reg < 4; ++reg) {
        int row = rbase + reg;
        float di = (row < N_NODES) ? dinv[row] : 0.f;
        #pragma unroll
        for (int nt = 0; nt < 4; ++nt)
            __builtin_nontemporal_store(f2bf(acc[nt][reg] * di),
                                        &H[(size_t)row * 64 + nt * 16 + l16]);
    }
}

// ---------------------------------------------------------------- aggregate -
// One wave per node, 4 independent waves/block, NO LDS, NO barriers.
// row_start and the 32 csr indices load through the scalar path (wave-uniform
// -> s_load into SGPRs), gather addresses are saddr + lane*2 (zero VALU math).
// All 32 gathers issue unconditionally (slots >= deg select the zero row
// N_NODES before use), so one overlapped latency window per node. deg>32
// (P ~ 1e-4) takes a scalar tail loop.
template <bool GELU>
__global__ __launch_bounds__(256) void k_aggregate(const u16* __restrict__ hs,
                                                   const int* __restrict__ csr_src,
                                                   const int* __restrict__ row_start,
                                                   const float* __restrict__ dinv,
                                                   const float* __restrict__ b,
                                                   void* __restrict__ outraw) {
    const int t = threadIdx.x;
    const int lane = t & 63;
    const int node = __builtin_amdgcn_readfirstlane(blockIdx.x * 4 + (t >> 6));
    const int jS = __builtin_amdgcn_readfirstlane(row_start[node]);
    const int jE = __builtin_amdgcn_readfirstlane(row_start[node + 1]);
    const int deg = jE - jS;
    const u16* __restrict__ colp = hs + lane;

    // uniform loads of up to 32 indices (reads past jE are in-bounds of the
    // csr allocation and get selected away below)
    int raw[32];
    #pragma unroll
    for (int i = 0; i < 32; ++i)
        raw[i] = __builtin_amdgcn_readfirstlane(csr_src[jS + i]);

    float acc = bf2f(colp[(size_t)node << 6]);   // self-loop
    u16 v[32];
    #pragma unroll
    for (int i = 0; i < 32; ++i) {
        int idx = (i < deg) ? raw[i] : N_NODES;   // scalar select, branchless
        v[i] = colp[(size_t)(unsigned)idx << 6];
    }
    #pragma unroll
    for (int i = 0; i < 32; ++i) acc += bf2f(v[i]);

    if (deg > 32) {   // rare scalar tail
        for (int j = jS + 32; j < jE; ++j) {
            int idx = __builtin_amdgcn_readfirstlane(csr_src[j]);
            acc += bf2f(colp[(size_t)(unsigned)idx << 6]);
        }
    }

    float r = dinv[node] * acc + b[lane];
    if (GELU) {
        r = 0.5f * r * (1.0f + erff(r * 0.70710678118654752f));
        ((u16*)outraw)[((size_t)node << 6) + lane] = f2bf(r);
    } else {
        ((float*)outraw)[((size_t)node << 6) + lane] = r;
    }
}

// ---------------------------------------------------------------- launch ----
extern "C" void kernel_launch(void* const* d_in, const int* in_sizes, int n_in,
                              void* d_out, int out_size, void* d_ws, size_t ws_size,
                              hipStream_t stream) {
    const float* x  = (const float*)d_in[0];
    const int* edge = (const int*)d_in[1];           // [2, N_EDGES] int32
    const float* W1 = (const float*)d_in[2];
    const float* b1 = (const float*)d_in[3];
    const float* W2 = (const float*)d_in[4];
    const float* b2 = (const float*)d_in[5];
    float* out = (float*)d_out;                      // [N_NODES, 64] fp32

    const int* src = edge;
    const int* dst = edge + N_EDGES;

    char* ws = (char*)d_ws;
    int*   bucketCursor = (int*)(ws);                 // 782 ints (pad 4096)
    int*   gBase        = (int*)(ws + 4096);          // 782 ints (pad 8192)
    int*   row_start    = (int*)(ws + 8192);          // N+1 (pad 408576)
    float* dinv         = (float*)(ws + 408576);      // N (pad 808960)
    int*   csr_src      = (int*)(ws + 808960);        // E (+32 slack, ends 7209088)
    u16*   hsb          = (u16*)(ws + 7209088);       // 100032*64 bf16 (ends 20013184)
    unsigned int* bins  = (unsigned int*)hsb;         // 8.13MB, dead before gemm1
    u16*   out1b        = (u16*)(ws + 20013184);      // 100032*64 bf16 (ends 32817280)

    const int nBlkBin  = (N_EDGES + BINCHUNK - 1) / BINCHUNK;  // 391
    const int nBlkGemm = (N_NODES + 63) / 64;                  // 1563 (covers 100032)
    const int nBlkAgg  = N_NODES / 4;                          // 25000

    // ---- CSR build ----
    hipMemsetAsync(bucketCursor, 0, NBUK * sizeof(int), stream);
    k_bin<<<nBlkBin, 256, 0, stream>>>(src, dst, bucketCursor, bins);
    k_bscan<<<1, 256, 0, stream>>>(bucketCursor, gBase, row_start);
    k_build<<<NBUK, 256, 0, stream>>>(bins, bucketCursor, gBase, row_start, dinv, csr_src);

    // ---- layer 1 ----
    k_gemm1<<<nBlkGemm, 256, 0, stream>>>(x, W1, dinv, hsb);
    k_aggregate<true><<<nBlkAgg, 256, 0, stream>>>(hsb, csr_src, row_start, dinv, b1, out1b);

    // ---- layer 2 ----
    k_gemm2<<<nBlkGemm, 256, 0, stream>>>(out1b, W2, dinv, hsb);
    k_aggregate<false><<<nBlkAgg, 256, 0, stream>>>(hsb, csr_src, row_start, dinv, b2, out);
}